// Round 17
// baseline (654.213 us; speedup 1.0000x reference)
//
#include <hip/hip_runtime.h>
#include <hip/hip_bf16.h>

// MILCellModel forward on MI355X. Round 17: fix R16's two flash bugs —
// (1) grid 256 -> 128 (blocks 128..255 were rogue: b=4..7 OOB reads = the
//     "30MB FETCH", racy writes into VT region; latent since R6).
// (2) LDS back to 62KB (single-buffer K/V + register prefetch; R16's 96KB
//     double-buffer exceeded the 64KB/workgroup limit).
// Decode qt=blk>>3, bh=blk&7 keeps the XCD swizzle (blk%8 == bh).
// B=4 N=1024 E=512 D=256 H=2 C=128 FF=1024 NQ=4 NCLS=24

typedef __bf16 bf16x8 __attribute__((ext_vector_type(8)));
typedef float  f32x4  __attribute__((ext_vector_type(4)));

__device__ __forceinline__ ushort f2b(float f) {
  __hip_bfloat16 h = __float2bfloat16(f);
  return *(ushort*)&h;
}
__device__ __forceinline__ float b2f(ushort u) {
  union { unsigned i; float f; } v; v.i = ((unsigned)u) << 16; return v.f;
}

// ---------- block reductions (256 threads) ----------
__device__ __forceinline__ float blk_sum256(float v, float* red) {
  int t = threadIdx.x;
  red[t] = v; __syncthreads();
  #pragma unroll
  for (int off = 128; off > 0; off >>= 1) {
    if (t < off) red[t] += red[t + off];
    __syncthreads();
  }
  float r = red[0]; __syncthreads();
  return r;
}

// ---------- staging helpers: 8 contiguous elements -> bf16 LDS ----------
__device__ __forceinline__ void stage8(const ushort* __restrict__ src, ushort* dst) {
  *(uint4*)dst = *(const uint4*)src;
}
__device__ __forceinline__ void stage8(const float* __restrict__ src, ushort* dst) {
  float4 a = ((const float4*)src)[0];
  float4 b = ((const float4*)src)[1];
  ushort4 o0, o1;
  o0.x = f2b(a.x); o0.y = f2b(a.y); o0.z = f2b(a.z); o0.w = f2b(a.w);
  o1.x = f2b(b.x); o1.y = f2b(b.y); o1.z = f2b(b.z); o1.w = f2b(b.w);
  *(ushort4*)dst = o0;
  *(ushort4*)(dst + 4) = o1;
}

// ---------- bf16 MFMA GEMM: C[M,N] = act(A[M,K] @ B^T + bias) ----------
template<typename CT, typename AT, typename WT, bool VSPLIT, bool GATS>
__global__ __launch_bounds__(256) void mfma_gemm(
    const AT* __restrict__ A, int lda,
    const WT* __restrict__ Bw, int ldb,
    const float* __restrict__ bias,
    CT* __restrict__ C, int ldc, int K, int relu,
    ushort* __restrict__ VT,
    const float* __restrict__ asrcW, const float* __restrict__ adstW,
    float* __restrict__ ASRC, float* __restrict__ ADST)
{
  __shared__ ushort As[64][40];
  __shared__ ushort Bs[128][40];
  int tid = threadIdx.x;
  int lane = tid & 63, wave = tid >> 6;
  int wm = wave >> 1, wn = wave & 1;
  int quad = lane >> 4, l16 = lane & 15;
  long mBase = blockIdx.y * 64, nBase = blockIdx.x * 128;

  f32x4 zero4 = {0.f, 0.f, 0.f, 0.f};
  f32x4 acc[2][4];
  #pragma unroll
  for (int i = 0; i < 2; i++)
    #pragma unroll
    for (int j = 0; j < 4; j++) acc[i][j] = zero4;

  for (int k0 = 0; k0 < K; k0 += 32) {
    {
      int r = tid >> 2, sg = (tid & 3) * 8;
      stage8(A + (mBase + r) * lda + k0 + sg, &As[r][sg]);
    }
    #pragma unroll
    for (int p = 0; p < 2; p++) {
      int idx = p * 256 + tid;
      int r = idx >> 2, sg = (idx & 3) * 8;
      stage8(Bw + (nBase + r) * ldb + k0 + sg, &Bs[r][sg]);
    }
    __syncthreads();
    bf16x8 af[2], bfr[4];
    #pragma unroll
    for (int i = 0; i < 2; i++)
      af[i] = *(const bf16x8*)&As[wm * 32 + i * 16 + l16][quad * 8];
    #pragma unroll
    for (int j = 0; j < 4; j++)
      bfr[j] = *(const bf16x8*)&Bs[wn * 64 + j * 16 + l16][quad * 8];
    #pragma unroll
    for (int i = 0; i < 2; i++)
      #pragma unroll
      for (int j = 0; j < 4; j++)
        acc[i][j] = __builtin_amdgcn_mfma_f32_16x16x32_bf16(af[i], bfr[j], acc[i][j], 0, 0, 0);
    __syncthreads();
  }
  #pragma unroll
  for (int i = 0; i < 2; i++) {
    #pragma unroll
    for (int j = 0; j < 4; j++) {
      long col = nBase + wn * 64 + j * 16 + l16;
      float bv = bias ? bias[col] : 0.f;
      long row0 = mBase + wm * 32 + i * 16 + quad * 4;
      if (VSPLIT && col >= 512) {
        int cm = (int)col - 512, hh = cm >> 7, cc = cm & 127;
        long bidx = row0 >> 10, n0 = row0 & 1023;
        ushort4 o;
        o.x = f2b(acc[i][j][0] + bv);
        o.y = f2b(acc[i][j][1] + bv);
        o.z = f2b(acc[i][j][2] + bv);
        o.w = f2b(acc[i][j][3] + bv);
        *(ushort4*)&VT[(((bidx * 2 + hh) * 128 + cc) << 10) + n0] = o;
      } else {
        #pragma unroll
        for (int r = 0; r < 4; r++) {
          float v = acc[i][j][r] + bv;
          if (relu) v = fmaxf(v, 0.f);
          if constexpr (sizeof(CT) == 2) C[(row0 + r) * ldc + col] = f2b(v);
          else                           C[(row0 + r) * ldc + col] = v;
        }
      }
    }
  }
  if constexpr (GATS) {
    __shared__ float RS[64][2], RD[64][2];
    float ps[2][4], pd[2][4];
    #pragma unroll
    for (int i = 0; i < 2; i++)
      #pragma unroll
      for (int r = 0; r < 4; r++) { ps[i][r] = 0.f; pd[i][r] = 0.f; }
    #pragma unroll
    for (int j = 0; j < 4; j++) {
      long col = nBase + wn * 64 + j * 16 + l16;
      float ws = asrcW[col], wd = adstW[col];
      #pragma unroll
      for (int i = 0; i < 2; i++)
        #pragma unroll
        for (int r = 0; r < 4; r++) {
          ps[i][r] += acc[i][j][r] * ws;
          pd[i][r] += acc[i][j][r] * wd;
        }
    }
    #pragma unroll
    for (int off = 1; off < 16; off <<= 1)
      #pragma unroll
      for (int i = 0; i < 2; i++)
        #pragma unroll
        for (int r = 0; r < 4; r++) {
          ps[i][r] += __shfl_xor(ps[i][r], off);
          pd[i][r] += __shfl_xor(pd[i][r], off);
        }
    if (l16 == 0) {
      #pragma unroll
      for (int i = 0; i < 2; i++)
        #pragma unroll
        for (int r = 0; r < 4; r++) {
          int row = wm * 32 + i * 16 + quad * 4 + r;
          RS[row][wn] = ps[i][r];
          RD[row][wn] = pd[i][r];
        }
    }
    __syncthreads();
    if (tid < 64) {
      long gr = mBase + tid;
      ASRC[gr * 2 + blockIdx.x] = RS[tid][0] + RS[tid][1];
      ADST[gr * 2 + blockIdx.x] = RD[tid][0] + RD[tid][1];
    }
  }
}

template<typename CT, typename AT, typename WT>
static void mgemm(hipStream_t st, const AT* A, int lda, const WT* B, int ldb,
                  const float* bias, CT* C, int ldc, int M, int N, int K, int relu) {
  dim3 grid(N / 128, M / 64);
  mfma_gemm<CT, AT, WT, false, false><<<grid, 256, 0, st>>>(
      A, lda, B, ldb, bias, C, ldc, K, relu, nullptr, nullptr, nullptr, nullptr, nullptr);
}
template<typename AT, typename WT>
static void mgemm_vt(hipStream_t st, const AT* A, int lda, const WT* B, int ldb,
                     const float* bias, ushort* C, int ldc, int M, int N, int K, ushort* VT) {
  dim3 grid(N / 128, M / 64);
  mfma_gemm<ushort, AT, WT, true, false><<<grid, 256, 0, st>>>(
      A, lda, B, ldb, bias, C, ldc, K, 0, VT, nullptr, nullptr, nullptr, nullptr);
}
template<typename AT, typename WT>
static void mgemm_gat(hipStream_t st, const AT* A, int lda, const WT* B, int ldb,
                      float* C, int ldc, int M, int N, int K,
                      const float* asrcW, const float* adstW, float* AS, float* AD) {
  dim3 grid(N / 128, M / 64);
  mfma_gemm<float, AT, WT, false, true><<<grid, 256, 0, st>>>(
      A, lda, B, ldb, nullptr, C, ldc, K, 0, nullptr, asrcW, adstW, AS, AD);
}

// ---------- fused pos-embed MLP (MFMA, weights LDS-resident) ----------
__global__ __launch_bounds__(256) void pos_mlp(
    const float* __restrict__ cellp, const float* __restrict__ tab,
    const float* __restrict__ W1, const float* __restrict__ b1,
    const float* __restrict__ W2, const float* __restrict__ b2,
    float* __restrict__ X, ushort* __restrict__ Xb)
{
  __shared__ ushort Es[64][136];
  __shared__ ushort Bs[128][136];
  __shared__ ushort H1s[64][136];
  int tid = threadIdx.x;
  int lane = tid & 63, wave = tid >> 6;
  int wm = wave >> 1, wn = wave & 1;
  int quad = lane >> 4, l16 = lane & 15;
  int r0 = blockIdx.x * 64, c = blockIdx.y;

  #pragma unroll
  for (int p = 0; p < 4; p++) {
    int idx = p * 256 + tid;
    int r = idx >> 4, c8 = (idx & 15) * 8;
    float pos = cellp[(r0 + r) * 2 + c];
    pos = fminf(fmaxf(pos, 0.f), 1000.f);
    int pi = (int)pos;
    stage8(tab + ((long)(c * 1001 + pi)) * 128 + c8, &Es[r][c8]);
  }
  #pragma unroll
  for (int p = 0; p < 8; p++) {
    int idx = p * 256 + tid;
    int r = idx >> 4, c8 = (idx & 15) * 8;
    stage8(W1 + ((long)(c * 128 + r)) * 128 + c8, &Bs[r][c8]);
  }
  __syncthreads();

  f32x4 zero4 = {0.f, 0.f, 0.f, 0.f};
  f32x4 acc[2][4];
  #pragma unroll
  for (int i = 0; i < 2; i++)
    #pragma unroll
    for (int j = 0; j < 4; j++) acc[i][j] = zero4;
  #pragma unroll
  for (int ks = 0; ks < 4; ks++) {
    bf16x8 af[2], bfr[4];
    #pragma unroll
    for (int i = 0; i < 2; i++)
      af[i] = *(const bf16x8*)&Es[wm * 32 + i * 16 + l16][ks * 32 + quad * 8];
    #pragma unroll
    for (int j = 0; j < 4; j++)
      bfr[j] = *(const bf16x8*)&Bs[wn * 64 + j * 16 + l16][ks * 32 + quad * 8];
    #pragma unroll
    for (int i = 0; i < 2; i++)
      #pragma unroll
      for (int j = 0; j < 4; j++)
        acc[i][j] = __builtin_amdgcn_mfma_f32_16x16x32_bf16(af[i], bfr[j], acc[i][j], 0, 0, 0);
  }
  #pragma unroll
  for (int i = 0; i < 2; i++)
    #pragma unroll
    for (int j = 0; j < 4; j++) {
      int col = wn * 64 + j * 16 + l16;
      float bv = b1[c * 128 + col];
      #pragma unroll
      for (int r = 0; r < 4; r++) {
        int row = wm * 32 + i * 16 + quad * 4 + r;
        H1s[row][col] = f2b(fmaxf(acc[i][j][r] + bv, 0.f));
      }
    }
  __syncthreads();
  #pragma unroll
  for (int p = 0; p < 8; p++) {
    int idx = p * 256 + tid;
    int r = idx >> 4, c8 = (idx & 15) * 8;
    stage8(W2 + ((long)(c * 128 + r)) * 128 + c8, &Bs[r][c8]);
  }
  __syncthreads();
  #pragma unroll
  for (int i = 0; i < 2; i++)
    #pragma unroll
    for (int j = 0; j < 4; j++) acc[i][j] = zero4;
  #pragma unroll
  for (int ks = 0; ks < 4; ks++) {
    bf16x8 af[2], bfr[4];
    #pragma unroll
    for (int i = 0; i < 2; i++)
      af[i] = *(const bf16x8*)&H1s[wm * 32 + i * 16 + l16][ks * 32 + quad * 8];
    #pragma unroll
    for (int j = 0; j < 4; j++)
      bfr[j] = *(const bf16x8*)&Bs[wn * 64 + j * 16 + l16][ks * 32 + quad * 8];
    #pragma unroll
    for (int i = 0; i < 2; i++)
      #pragma unroll
      for (int j = 0; j < 4; j++)
        acc[i][j] = __builtin_amdgcn_mfma_f32_16x16x32_bf16(af[i], bfr[j], acc[i][j], 0, 0, 0);
  }
  #pragma unroll
  for (int i = 0; i < 2; i++)
    #pragma unroll
    for (int j = 0; j < 4; j++) {
      int col = wn * 64 + j * 16 + l16;
      float bv = b2[c * 128 + col];
      #pragma unroll
      for (int r = 0; r < 4; r++) {
        long row = r0 + wm * 32 + i * 16 + quad * 4 + r;
        long idx = row * 256 + c * 128 + col;
        float v = X[idx] + (acc[i][j][r] + bv);
        X[idx] = v;
        Xb[idx] = f2b(v);
      }
    }
}

// ---------- split-K skinny GEMM (M rows <= 16) ----------
template<int M_>
__global__ __launch_bounds__(256) void skinny_gemm(
    const float* __restrict__ A, int lda,
    const float* __restrict__ W, int K,
    float* __restrict__ P, int N, int slice)
{
  __shared__ float Asl[M_ * 192];
  __shared__ float Pr[4][M_][64];
  int tid = threadIdx.x;
  int ks = blockIdx.y;
  int kbeg = ks * slice;
  int kend = min(K, kbeg + slice);
  int sl = kend - kbeg;
  for (int idx = tid; idx < M_ * sl; idx += 256) {
    int m = idx / sl, k = idx - m * sl;
    Asl[m * sl + k] = A[(long)m * lda + kbeg + k];
  }
  __syncthreads();
  int n = blockIdx.x * 64 + (tid & 63);
  int sub = tid >> 6;
  int sl4 = (sl + 3) >> 2;
  int k0 = kbeg + sub * sl4;
  int k1 = min(kend, k0 + sl4);
  float acc[M_];
  #pragma unroll
  for (int m = 0; m < M_; m++) acc[m] = 0.f;
  if (n < N) {
    const float* wr = W + (long)n * K;
    for (int k = k0; k < k1; k++) {
      float w = wr[k];
      int kl = k - kbeg;
      #pragma unroll
      for (int m = 0; m < M_; m++) acc[m] += w * Asl[m * sl + kl];
    }
  }
  #pragma unroll
  for (int m = 0; m < M_; m++) Pr[sub][m][tid & 63] = acc[m];
  __syncthreads();
  if (sub == 0 && n < N) {
    #pragma unroll
    for (int m = 0; m < M_; m++) {
      float s = Pr[0][m][tid] + Pr[1][m][tid] + Pr[2][m][tid] + Pr[3][m][tid];
      P[((long)(ks * M_ + m)) * N + n] = s;
    }
  }
}

__global__ __launch_bounds__(256) void skinny_epi(
    const float* __restrict__ P, const float* __restrict__ bias,
    float* __restrict__ out, int M, int N, int KS, int relu)
{
  int idx = blockIdx.x * 256 + threadIdx.x;
  if (idx >= M * N) return;
  int m = idx / N, n = idx - m * N;
  float s = bias[n];
  for (int ks = 0; ks < KS; ks++) s += P[((long)(ks * M + m)) * N + n];
  if (relu) s = fmaxf(s, 0.f);
  out[(long)m * N + n] = s;
}

template<int M_>
static void sgemm(hipStream_t st, const float* A, int lda, const float* W, int K,
                  const float* bias, float* out, float* P, int N, int KS, int relu) {
  int slice = (K + KS - 1) / KS;
  dim3 grid((N + 63) / 64, KS);
  skinny_gemm<M_><<<grid, 256, 0, st>>>(A, lda, W, K, P, N, slice);
  skinny_epi<<<(M_ * N + 255) / 256, 256, 0, st>>>(P, bias, out, M_, N, KS, relu);
}

// ---------- bag stats: pn = (cellposes - mean) / (std + 1e-8) ----------
__global__ __launch_bounds__(256) void bag_stats(const float* __restrict__ cp, float* __restrict__ PN) {
  int b = blockIdx.x, tid = threadIdx.x;
  __shared__ float red[256];
  for (int c = 0; c < 2; c++) {
    float s = 0.f;
    for (int n = tid; n < 1024; n += 256) s += cp[((b << 10) + n) * 2 + c];
    float mean = blk_sum256(s, red) * (1.f / 1024.f);
    s = 0.f;
    for (int n = tid; n < 1024; n += 256) { float d = cp[((b << 10) + n) * 2 + c] - mean; s += d * d; }
    float var = blk_sum256(s, red) * (1.f / 1024.f);
    float inv = 1.f / (sqrtf(var) + 1e-8f);
    for (int n = tid; n < 1024; n += 256)
      PN[((b << 10) + n) * 2 + c] = (cp[((b << 10) + n) * 2 + c] - mean) * inv;
  }
}

// ---------- kNN: wave-cooperative iterative argmin (8x u64 shfl-min) ----------
__global__ __launch_bounds__(256) void knn_sel(const float* __restrict__ PN,
                                               int* __restrict__ NBR) {
  int blk = blockIdx.x;               // 512 blocks
  int b = blk >> 7, grp = blk & 127;  // 8 targets per block
  int tid = threadIdx.x;
  int wave = tid >> 6, lane = tid & 63;
  __shared__ float px[1024], py[1024];
  for (int i = tid; i < 1024; i += 256) {
    px[i] = PN[((b << 10) + i) * 2 + 0];
    py[i] = PN[((b << 10) + i) * 2 + 1];
  }
  __syncthreads();
  #pragma unroll
  for (int sub = 0; sub < 2; sub++) {
    int t = grp * 8 + wave * 2 + sub;
    float tx = px[t], ty = py[t];
    float dloc[16];
    #pragma unroll
    for (int k = 0; k < 16; k++) {
      int s = lane + (k << 6);
      float dx = __fadd_rn(px[s], -tx), dy = __fadd_rn(py[s], -ty);
      float d2 = __fadd_rn(__fadd_rn(__fmul_rn(dx, dx), __fmul_rn(dy, dy)), 1e-12f);
      dloc[k] = sqrtf(d2);
    }
    int res[8];
    #pragma unroll
    for (int it = 0; it < 8; it++) {
      float bd = dloc[0]; int bk = 0;
      #pragma unroll
      for (int k = 1; k < 16; k++)
        if (dloc[k] < bd) { bd = dloc[k]; bk = k; }
      unsigned long long key =
          (((unsigned long long)__float_as_uint(bd)) << 32) | (unsigned)(lane + (bk << 6));
      #pragma unroll
      for (int off = 1; off < 64; off <<= 1) {
        unsigned long long o = __shfl_xor(key, off);
        if (o < key) key = o;
      }
      int widx = (int)(key & 0xffffffffu);
      res[it] = widx;
      if ((widx & 63) == lane) dloc[widx >> 6] = 3.4e38f;
    }
    if (lane < 8) NBR[((long)((b << 10) + t)) * 8 + lane] = res[lane];
  }
}

// ---------- GAT aggregate + residual + LN ----------
__global__ __launch_bounds__(256) void gat_aggr_ln(
    const float* __restrict__ Hh, const float* __restrict__ ASRC, const float* __restrict__ ADST,
    const int* __restrict__ NBR, const float* __restrict__ gbias,
    const float* __restrict__ lng, const float* __restrict__ lnb,
    float* __restrict__ X, ushort* __restrict__ Xb)
{
  int row = blockIdx.x, tid = threadIdx.x;
  int b = row >> 10;
  __shared__ int nb[8];
  __shared__ float w[2][8];
  __shared__ float red[256];
  if (tid < 8) {
    int v = NBR[(long)row * 8 + tid];
    nb[tid] = min(max(v, 0), 1023);
  }
  __syncthreads();
  if (tid < 16) {
    int i = tid & 7, h = tid >> 3;
    float e = ADST[row * 2 + h] + ASRC[((b << 10) + nb[i]) * 2 + h];
    w[h][i] = (e >= 0.f) ? e : 0.2f * e;
  }
  __syncthreads();
  if (tid < 2) {
    float m = -3.4e38f;
    for (int i = 0; i < 8; i++) m = fmaxf(m, w[tid][i]);
    float s = 0.f;
    for (int i = 0; i < 8; i++) { float e = expf(w[tid][i] - m); w[tid][i] = e; s += e; }
    float inv = 1.f / s;
    for (int i = 0; i < 8; i++) w[tid][i] *= inv;
  }
  __syncthreads();
  int h = tid >> 7, c = tid & 127;
  float acc = 0.f;
  #pragma unroll
  for (int i = 0; i < 8; i++)
    acc += w[h][i] * Hh[((long)((b << 10) + nb[i])) * 256 + h * 128 + c];
  float v = acc + gbias[tid] + X[(long)row * 256 + tid];
  float mean = blk_sum256(v, red) * (1.f / 256.f);
  float dv = v - mean;
  float var = blk_sum256(dv * dv, red) * (1.f / 256.f);
  float o = dv * rsqrtf(var + 1e-5f) * lng[tid] + lnb[tid];
  X[(long)row * 256 + tid] = o;
  Xb[(long)row * 256 + tid] = f2b(o);
}

// ---------- residual + LayerNorm, D=256, one wave per row ----------
__global__ __launch_bounds__(256) void add_ln4(const float* __restrict__ res,
    const float* __restrict__ Yv, const float* __restrict__ g, const float* __restrict__ b,
    float* __restrict__ out, ushort* __restrict__ outb)
{
  int wave = threadIdx.x >> 6, lane = threadIdx.x & 63;
  long row = blockIdx.x * 4 + wave;
  const float* yr = Yv + row * 256;
  const float* rr = res ? res + row * 256 : nullptr;
  float v[4];
  float s = 0.f;
  #pragma unroll
  for (int i = 0; i < 4; i++) {
    int d = lane + i * 64;
    float x = yr[d];
    if (rr) x += rr[d];
    v[i] = x; s += x;
  }
  #pragma unroll
  for (int off = 32; off > 0; off >>= 1) s += __shfl_xor(s, off);
  float mean = s * (1.f / 256.f);
  float vs = 0.f;
  #pragma unroll
  for (int i = 0; i < 4; i++) { float dv = v[i] - mean; vs += dv * dv; }
  #pragma unroll
  for (int off = 32; off > 0; off >>= 1) vs += __shfl_xor(vs, off);
  float rstd = rsqrtf(vs * (1.f / 256.f) + 1e-5f);
  #pragma unroll
  for (int i = 0; i < 4; i++) {
    int d = lane + i * 64;
    float o = (v[i] - mean) * rstd * g[d] + b[d];
    out[row * 256 + d] = o;
    if (outb) outb[row * 256 + d] = f2b(o);
  }
}

// ---------- LayerNorm (D=1024, head rows) ----------
__global__ __launch_bounds__(256) void add_ln_big(const float* __restrict__ Yv,
    const float* __restrict__ g, const float* __restrict__ b,
    float* __restrict__ out)
{
  int row = blockIdx.x, tid = threadIdx.x;
  __shared__ float red[256];
  float vals[4];
  float s = 0.f;
  #pragma unroll
  for (int i = 0; i < 4; i++) {
    int d = tid + (i << 8);
    float v = Yv[(long)row * 1024 + d];
    vals[i] = v; s += v;
  }
  float mean = blk_sum256(s, red) * (1.f / 1024.f);
  s = 0.f;
  #pragma unroll
  for (int i = 0; i < 4; i++) { float dv = vals[i] - mean; s += dv * dv; }
  float var = blk_sum256(s, red) * (1.f / 1024.f);
  float rstd = rsqrtf(var + 1e-5f);
  #pragma unroll
  for (int i = 0; i < 4; i++) {
    int d = tid + (i << 8);
    out[(long)row * 1024 + d] = (vals[i] - mean) * rstd * g[d] + b[d];
  }
}

// ---------- MFMA flash attention (128 blocks, XCD swizzle, reg prefetch) ----------
__global__ __launch_bounds__(256) void flash_mfma(const ushort* __restrict__ QKV,
                                                  const ushort* __restrict__ VT,
                                                  ushort* __restrict__ O)
{
  const float scale = 0.08838834764831845f;
  int blk = blockIdx.x;              // 128 blocks == 16 qt x 8 bh (no rogue blocks)
  int qt = blk >> 3, bh = blk & 7;   // XCD swizzle: blk%8 == bh -> K/V L2-resident
  int b = bh >> 1, h = bh & 1;
  const ushort* qkg = QKV + (long)b * 1024 * 768 + h * 128;
  const ushort* vtg = VT + ((long)bh << 17);

  __shared__ ushort Qs[64][136];
  __shared__ ushort Ks[64][136];
  __shared__ ushort Vt[128][72];
  __shared__ ushort Ps[4][16][72];   // total 62464 B (< 64KB limit)

  int tid = threadIdx.x;
  int wave = tid >> 6, lane = tid & 63;
  int quad = lane >> 4, l16 = lane & 15;

  uint4 kr[4], vr[4];
  // prefetch tile 0 into registers
  #pragma unroll
  for (int p = 0; p < 4; p++) {
    int idx = p * 256 + tid;
    int r = idx >> 4, c8 = (idx & 15) * 8;
    kr[p] = *(const uint4*)(qkg + (long)r * 768 + 256 + c8);
    int c = idx >> 3, k8 = (idx & 7) * 8;
    vr[p] = *(const uint4*)(vtg + ((long)c << 10) + k8);
  }
  // stage Q
  #pragma unroll
  for (int p = 0; p < 4; p++) {
    int idx = p * 256 + tid;
    int r = idx >> 4, c8 = (idx & 15) * 8;
    *(uint4*)&Qs[r][c8] = *(const uint4*)(qkg + (long)(qt * 64 + r) * 768 + c8);
  }
  // write tile 0 to LDS
  #pragma unroll
  for (int p = 0; p < 4; p++) {
    int idx = p * 256 + tid;
    int r = idx >> 4, c8 = (idx & 15) * 8;
    *(uint4*)&Ks[r][c8] = kr[p];
    int c = idx >> 3, k8 = (idx & 7) * 8;
    *(uint4*)&Vt[c][k8] = vr[p];
  }
  __syncthreads();
  bf16x8 af[4];
  #pragma unroll
  for (int ks = 0; ks < 4; ks++)
    af[ks] = *(const bf16x8*)&Qs[wave * 16 + l16][ks * 32 + quad * 8];

  f32x4 Oacc[8];
  f32x4 zero4 = {0.f, 0.f, 0.f, 0.f};
  #pragma unroll
  for (int j = 0; j < 8; j++) Oacc[j] = zero4;
  float mr[4], lr[4];
  #pragma unroll
  for (int r = 0; r < 4; r++) { mr[r] = -3.4e38f; lr[r] = 0.f; }

  for (int kt = 0; kt < 16; kt++) {
    // prefetch next tile to registers (overlaps QK + softmax below)
    if (kt < 15) {
      #pragma unroll
      for (int p = 0; p < 4; p++) {
        int idx = p * 256 + tid;
        int r = idx >> 4, c8 = (idx & 15) * 8;
        kr[p] = *(const uint4*)(qkg + (long)((kt + 1) * 64 + r) * 768 + 256 + c8);
        int c = idx >> 3, k8 = (idx & 7) * 8;
        vr[p] = *(const uint4*)(vtg + ((long)c << 10) + (kt + 1) * 64 + k8);
      }
    }
    // S = Q K^T
    f32x4 acc[4];
    #pragma unroll
    for (int j = 0; j < 4; j++) acc[j] = zero4;
    #pragma unroll
    for (int ks = 0; ks < 4; ks++) {
      #pragma unroll
      for (int j = 0; j < 4; j++) {
        bf16x8 kb = *(const bf16x8*)&Ks[j * 16 + l16][ks * 32 + quad * 8];
        acc[j] = __builtin_amdgcn_mfma_f32_16x16x32_bf16(af[ks], kb, acc[j], 0, 0, 0);
      }
    }
    // online softmax
    float sv[4][4], tmax[4];
    #pragma unroll
    for (int r = 0; r < 4; r++) tmax[r] = -3.4e38f;
    #pragma unroll
    for (int j = 0; j < 4; j++)
      #pragma unroll
      for (int r = 0; r < 4; r++) {
        float x = acc[j][r] * scale;
        sv[j][r] = x;
        tmax[r] = fmaxf(tmax[r], x);
      }
    #pragma unroll
    for (int off = 1; off < 16; off <<= 1)
      #pragma unroll
      for (int r = 0; r < 4; r++) tmax[r] = fmaxf(tmax[r], __shfl_xor(tmax[r], off));
    float alpha[4], rsum[4];
    #pragma unroll
    for (int r = 0; r < 4; r++) {
      float mn = fmaxf(mr[r], tmax[r]);
      alpha[r] = expf(mr[r] - mn);
      mr[r] = mn;
      rsum[r] = 0.f;
    }
    #pragma unroll
    for (int j = 0; j < 4; j++)
      #pragma unroll
      for (int r = 0; r < 4; r++) {
        float p = expf(sv[j][r] - mr[r]);
        sv[j][r] = p;
        rsum[r] += p;
      }
    #pragma unroll
    for (int off = 1; off < 16; off <<= 1)
      #pragma unroll
      for (int r = 0; r < 4; r++) rsum[r] += __shfl_xor(rsum[r], off);
    #pragma unroll
    for (int r = 0; r < 4; r++) lr[r] = lr[r] * alpha[r] + rsum[r];
    // P -> LDS (wave-private); rescale O
    #pragma unroll
    for (int j = 0; j < 4; j++)
      #pragma unroll
      for (int r = 0; r < 4; r++)
        Ps[wave][quad * 4 + r][j * 16 + l16] = f2b(sv[j][r]);
    #pragma unroll
    for (int jj = 0; jj < 8; jj++)
      #pragma unroll
      for (int r = 0; r < 4; r++) Oacc[jj][r] *= alpha[r];
    __syncthreads();   // A: Ps visible; all QK reads of Ks done
    // Ks is dead this iteration -> write prefetched K now (overlaps PV)
    if (kt < 15) {
      #pragma unroll
      for (int p = 0; p < 4; p++) {
        int idx = p * 256 + tid;
        int r = idx >> 4, c8 = (idx & 15) * 8;
        *(uint4*)&Ks[r][c8] = kr[p];
      }
    }
    // O += P V
    #pragma unroll
    for (int s = 0; s < 2; s++) {
      bf16x8 pa = *(const bf16x8*)&Ps[wave][l16][s * 32 + quad * 8];
      #pragma unroll
      for (int jj = 0; jj < 8; jj++) {
        bf16x8 vb = *(const bf16x8*)&Vt[jj * 16 + l16][s * 32 + quad * 8];
        Oacc[jj] = __builtin_amdgcn_mfma_f32_16x16x32_bf16(pa, vb, Oacc[jj], 0, 0, 0);
      }
    }
    __syncthreads();   // B: PV reads of Vt done; Ks writes visible
    if (kt < 15) {
      #pragma unroll
      for (int p = 0; p < 4; p++) {
        int idx = p * 256 + tid;
        int c = idx >> 3, k8 = (idx & 7) * 8;
        *(uint4*)&Vt[c][k8] = vr[p];
      }
    }
    __syncthreads();   // C: Vt writes visible before next iteration
  }
  long row0 = (long)b * 1024 + qt * 64 + wave * 16 + quad * 4;
  #pragma unroll
  for (int jj = 0; jj < 8; jj++) {
    int col = h * 128 + jj * 16 + l16;
    #pragma unroll
    for (int r = 0; r < 4; r++)
      O[(row0 + r) * 256 + col] = f2b(Oacc[jj][r] / lr[r]);
  }
}

// ---------- split-K pooling attention ----------
__global__ __launch_bounds__(128) void pool_split(
    const float* __restrict__ qe, const float* __restrict__ pinW, const float* __restrict__ pinB,
    const float* __restrict__ srand, const ushort* __restrict__ KV,
    float* __restrict__ PM, float* __restrict__ PL, float* __restrict__ PO)
{
  int cid = blockIdx.x;
  int id = blockIdx.y;
  int h = id & 1, nq = (id >> 1) & 3, b = id >> 3;
  int tid = threadIdx.x;
  __shared__ float qs[128];
  __shared__ float eg[128];
  __shared__ float red[128];
  {
    float a = pinB[h * 128 + tid];
    const float* wr = pinW + ((long)(h * 128 + tid)) * 256;
    const float* qr = qe + nq * 256;
    for (int i = 0; i < 256; i++) a += qr[i] * wr[i];
    qs[tid] = a;
  }
  __syncthreads();
  const float scale = 0.08838834764831845f;
  int s = cid * 128 + tid;
  float d = 0.f;
  {
    const ushort* kr = KV + ((long)((b << 10) + s)) * 512 + h * 128;
    #pragma unroll
    for (int c8 = 0; c8 < 128; c8 += 8) {
      uint4 kv4 = *(const uint4*)(kr + c8);
      const ushort* kp = (const ushort*)&kv4;
      #pragma unroll
      for (int j = 0; j < 8; j++) d += qs[c8 + j] * b2f(kp[j]);
    }
  }
  float lg = d * scale + ((srand[nq * 1024 + s] < 0.3f) ? 0.f : -1e9f);
  red[tid] = lg; __syncthreads();
  for (int off = 64; off > 0; off >>= 1) { if (tid < off) red[tid] = fmaxf(red[tid], red[tid + off]); __syncthreads(); }
  float m = red[0]; __syncthreads();
  float e = expf(lg - m);
  eg[tid] = e;
  red[tid] = e; __syncthreads();
  for (int off = 64; off > 0; off >>= 1) { if (tid < off) red[tid] += red[tid + off]; __syncthreads(); }
  float l = red[0];
  __syncthreads();
  float o = 0.f;
  const ushort* vbase = KV + ((long)((b << 10) + cid * 128)) * 512 + 256 + h * 128 + tid;
  for (int ss = 0; ss < 128; ss++)
    o += eg[ss] * b2f(vbase[(long)ss * 512]);
  int part = id * 8 + cid;
  PO[(long)part * 128 + tid] = o;
  if (tid == 0) { PM[part] = m; PL[part] = l; }
}

__global__ __launch_bounds__(128) void pool_merge(
    const float* __restrict__ PM, const float* __restrict__ PL, const float* __restrict__ PO,
    float* __restrict__ ATTP)
{
  int id = blockIdx.x;
  int h = id & 1, nq = (id >> 1) & 3, b = id >> 3;
  int tid = threadIdx.x;
  float m = -3.4e38f;
  #pragma unroll
  for (int c = 0; c < 8; c++) m = fmaxf(m, PM[id * 8 + c]);
  float l = 0.f, o = 0.f;
  #pragma unroll
  for (int c = 0; c < 8; c++) {
    float w = expf(PM[id * 8 + c] - m);
    l += PL[id * 8 + c] * w;
    o += PO[(long)(id * 8 + c) * 128 + tid] * w;
  }
  ATTP[(b * 4 + nq) * 256 + h * 128 + tid] = o / l;
}

// ---------- column-mean partials ----------
__global__ __launch_bounds__(256) void col_mean_part(const float* __restrict__ X,
                                                     float* __restrict__ PSUM)
{
  int blk = blockIdx.x;
  int b = blk >> 4, ch = blk & 15;
  int d = threadIdx.x;
  float s = 0.f;
  int n0 = ch * 64;
  const float* xr = X + ((long)((b << 10) + n0)) * 256 + d;
  #pragma unroll 4
  for (int n = 0; n < 64; n++) s += xr[(long)n * 256];
  PSUM[(long)blk * 256 + d] = s;
}

__global__ __launch_bounds__(256) void combined_merge(const float* __restrict__ PSUM,
    const float* __restrict__ ATTO, float* __restrict__ CMB)
{
  int b = blockIdx.x, d = threadIdx.x;
  float s = 0.f;
  #pragma unroll
  for (int ch = 0; ch < 16; ch++) s += PSUM[(long)(b * 16 + ch) * 256 + d];
  CMB[b * 1280 + d] = s * (1.f / 1024.f);
  #pragma unroll
  for (int q = 0; q < 4; q++)
    CMB[b * 1280 + 256 + q * 256 + d] = ATTO[(b * 4 + q) * 256 + d];
}

__global__ void store_out(const float* __restrict__ src, float* __restrict__ dst, int n) {
  int i = blockIdx.x * blockDim.x + threadIdx.x;
  if (i < n) dst[i] = src[i];
}
__global__ void fill_out_zero(float* __restrict__ dst, int n) {
  int i = blockIdx.x * blockDim.x + threadIdx.x;
  if (i < n) dst[i] = 0.f;
}

extern "C" void kernel_launch(void* const* d_in, const int* in_sizes, int n_in,
                              void* d_out, int out_size, void* d_ws, size_t ws_size,
                              hipStream_t stream)
{
  const float* inp      = (const float*)d_in[0];
  const float* cellp    = (const float*)d_in[1];
  const float* srand    = (const float*)d_in[2];
  const float* emb_W    = (const float*)d_in[3];
  const float* emb_b    = (const float*)d_in[4];
  const float* pe_tab   = (const float*)d_in[5];
  const float* pe_W1    = (const float*)d_in[6];
  const float* pe_b1    = (const float*)d_in[7];
  const float* pe_W2    = (const float*)d_in[8];
  const float* pe_b2    = (const float*)d_in[9];
  const float* gat_W    = (const float*)d_in[10];
  const float* gat_asrc = (const float*)d_in[11];
  const float* gat_adst = (const float*)d_in[12];
  const float* gat_b    = (const float*)d_in[13];
  const float* ln_g     = (const float*)d_in[14];
  const float* ln_b     = (const float*)d_in[15];
  const float* qkv_W    = (const float*)d_in[16];
  const float* qkv_b    = (const float*)d_in[17];
  const float* out_W    = (const float*)d_in[18];
  const float* out_b    = (const float*)d_in[19];
  const float* ff1_W    = (const float*)d_in[20];
  const float* ff1_b    = (const float*)d_in[21];
  const float* ff2_W    = (const float*)d_in[22];
  const float* ff2_b    = (const float*)d_in[23];
  const float* ln1_g    = (const float*)d_in[24];
  const float* ln1_b    = (const float*)d_in[25];
  const float* ln2_g    = (const float*)d_in[26];
  const float* ln2_b    = (const float*)d_in[27];
  const float* q_emb    = (const float*)d_in[28];
  const float* pin_W    = (const float*)d_in[29];
  const float* pin_b    = (const float*)d_in[30];
  const float* pout_W   = (const float*)d_in[31];
  const float* pout_b   = (const float*)d_in[32];
  const float* m1_W     = (const float*)d_in[33];
  const float* m1_b     = (const float*)d_in[34];
  const float* mln1_g   = (const float*)d_in[35];
  const float* mln1_b   = (const float*)d_in[36];
  const float* m2_W     = (const float*)d_in[37];
  const float* m2_b     = (const float*)d_in[38];
  const float* mln2_g   = (const float*)d_in[39];
  const float* mln2_b   = (const float*)d_in[40];
  const float* m3_W     = (const float*)d_in[41];
  const float* m3_b     = (const float*)d_in[42];
  const float* c1_W     = (const float*)d_in[43];
  const float* c1_b     = (const float*)d_in[44];
  const float* c2_W     = (const float*)d_in[45];
  const float* c2_b     = (const float*)d_in[46];
  const float* c3_W     = (const float*)d_in[47];
  const float* c3_b     = (const float*)d_in[48];
  const float* c4_W     = (const float*)d_in[49];
  const float* c4_b     = (const float*)d_in[50];
  (void)in_sizes; (void)n_in;

  // ---- workspace (bytes, 256-aligned; ~20.7 MB) ----
  char* base = (char*)d_ws;
  size_t off = 0;
  auto alloc = [&](size_t bytes) { void* p = base + off; off += (bytes + 255) & ~size_t(255); return p; };
  float* PN    = (float*)alloc(32768);
  float* AS    = (float*)alloc(32768);
  float* AD    = (float*)alloc(32768);
  float* ATTP  = (float*)alloc(16384);
  float* ATTO  = (float*)alloc(16384);
  float* CMB   = (float*)alloc(20480);
  float* Ha    = (float*)alloc(16384);
  float* Hb    = (float*)alloc(16384);
  float* Hc    = (float*)alloc(16640);
  float* Hd    = (float*)alloc(8192);
  float* He    = (float*)alloc(4096);
  float* Hf    = (float*)alloc(512);
  float* Pk    = (float*)alloc(262144);
  float* PPM   = (float*)alloc(1024);
  float* PPL   = (float*)alloc(1024);
  float* PPO   = (float*)alloc(131072);
  float* PSUM  = (float*)alloc(65536);
  int*   NBR   = (int*)alloc(131072);
  float* X     = (float*)alloc(4194304);
  ushort* Xb   = (ushort*)alloc(2097152);
  char*  Rq    = (char*)alloc(6291456);           // QKVb | F2 | KVb
  char*  Rf    = (char*)alloc(4194304);           // Ob | VT | FFBb(lo)
  float*  F1   = (float*)alloc(4194304);          // GAT h | FFBb(hi)
  ushort* QKVb = (ushort*)Rq;
  float*  F2   = (float*)Rq;
  ushort* KVb  = (ushort*)Rq;
  ushort* Ob   = (ushort*)Rf;
  ushort* VT   = (ushort*)(Rf + 2097152);
  ushort* FFBb = (ushort*)Rf;                     // [4096,1024] bf16 spans Rf+F1
  if (ws_size < off) { fill_out_zero<<<1, 128, 0, stream>>>((float*)d_out, out_size); return; }

  // ---- graph construction ----
  bag_stats<<<4, 256, 0, stream>>>(cellp, PN);
  knn_sel<<<512, 256, 0, stream>>>(PN, NBR);

  // ---- embedding + positional MLP (MFMA; emits X and Xb) ----
  mgemm<float>(stream, inp, 512, emb_W, 512, emb_b, X, 256, 4096, 256, 512, 0);
  pos_mlp<<<dim3(64, 2), 256, 0, stream>>>(cellp, pe_tab, pe_W1, pe_b1, pe_W2, pe_b2, X, Xb);

  // ---- 2x GAT (scores fused into GEMM epilogue) ----
  for (int l = 0; l < 2; l++) {
    mgemm_gat(stream, Xb, 256, gat_W + l * 65536, 256, F1, 256, 4096, 256, 256,
              gat_asrc + l * 256, gat_adst + l * 256, AS, AD);
    gat_aggr_ln<<<4096, 256, 0, stream>>>(F1, AS, AD, NBR, gat_b + l * 256, ln_g, ln_b, X, Xb);
  }

  // ---- 2x Transformer encoder layer (single-chunk FFN) ----
  for (int l = 0; l < 2; l++) {
    mgemm_vt(stream, Xb, 256, qkv_W + (long)l * 768 * 256, 256, qkv_b + l * 768,
             QKVb, 768, 4096, 768, 256, VT);
    flash_mfma<<<128, 256, 0, stream>>>(QKVb, VT, Ob);
    mgemm<float>(stream, Ob, 256, out_W + l * 65536, 256, out_b + l * 256, F2, 256,
                 4096, 256, 256, 0);
    add_ln4<<<1024, 256, 0, stream>>>(X, F2, ln1_g + l * 256, ln1_b + l * 256, X, Xb);
    mgemm<ushort>(stream, Xb, 256, ff1_W + l * 262144, 256, ff1_b + l * 1024,
                  FFBb, 1024, 4096, 1024, 256, 1);
    mgemm<float>(stream, FFBb, 1024, ff2_W + l * 262144, 1024, ff2_b + l * 256,
                 F2, 256, 4096, 256, 1024, 0);
    add_ln4<<<1024, 256, 0, stream>>>(X, F2, ln2_g + l * 256, ln2_b + l * 256, X, Xb);
  }

  // ---- final LN ----
  add_ln4<<<1024, 256, 0, stream>>>((const float*)nullptr, X, ln_g, ln_b, X, Xb);

  // ---- pooling (split-K flash-decode style) ----
  mgemm<ushort>(stream, Xb, 256, pin_W + 65536, 256, pin_b + 256, KVb, 512, 4096, 512, 256, 0);
  pool_split<<<dim3(8, 32), 128, 0, stream>>>(q_emb, pin_W, pin_b, srand, KVb, PPM, PPL, PPO);
  pool_merge<<<32, 128, 0, stream>>>(PPM, PPL, PPO, ATTP);
  sgemm<16>(stream, ATTP, 256, pout_W, 256, pout_b, ATTO, Pk, 256, 2, 0);
  col_mean_part<<<64, 256, 0, stream>>>(X, PSUM);
  combined_merge<<<4, 256, 0, stream>>>(PSUM, ATTO, CMB);

  // ---- MLP head (fp32, split-K skinny GEMMs) ----
  sgemm<4>(stream, CMB, 1280, m1_W, 1280, m1_b, Ha, Pk, 1024, 8, 1);
  add_ln_big<<<4, 256, 0, stream>>>(Ha, mln1_g, mln1_b, Ha);
  sgemm<4>(stream, Ha, 1024, m2_W, 1024, m2_b, Hb, Pk, 1024, 8, 1);
  add_ln_big<<<4, 256, 0, stream>>>(Hb, mln2_g, mln2_b, Hb);
  sgemm<4>(stream, Hb, 1024, m3_W, 1024, m3_b, Ha, Pk, 1024, 8, 0);
  sgemm<4>(stream, Ha, 1024, c1_W, 1024, c1_b, Hc, Pk, 1032, 8, 1);
  sgemm<4>(stream, Hc, 1032, c2_W, 1032, c2_b, Hd, Pk, 512, 8, 1);
  sgemm<4>(stream, Hd, 512, c3_W, 512, c3_b, He, Pk, 256, 4, 1);
  sgemm<4>(stream, He, 256, c4_W, 256, c4_b, Hf, Pk, 24, 2, 0);
  store_out<<<1, 128, 0, stream>>>(Hf, (float*)d_out, out_size);
}

// Round 18
// 591.033 us; speedup vs baseline: 1.1069x; 1.1069x over previous
//
#include <hip/hip_runtime.h>
#include <hip/hip_bf16.h>

// MILCellModel forward on MI355X. Round 18: split-K flash attention —
// R17 post-mortem: FETCH fixed (30->3.2MB) but reg-prefetch variant made each
// block slower (63us) and 128 blocks idle half the chip. Revert to R15's
// proven inner loop, split K-range across 2 blocks (256 blocks total, XCD
// swizzle kept), partials (m,l,O_bf16) merged by a small second kernel.
// B=4 N=1024 E=512 D=256 H=2 C=128 FF=1024 NQ=4 NCLS=24

typedef __bf16 bf16x8 __attribute__((ext_vector_type(8)));
typedef float  f32x4  __attribute__((ext_vector_type(4)));

__device__ __forceinline__ ushort f2b(float f) {
  __hip_bfloat16 h = __float2bfloat16(f);
  return *(ushort*)&h;
}
__device__ __forceinline__ float b2f(ushort u) {
  union { unsigned i; float f; } v; v.i = ((unsigned)u) << 16; return v.f;
}

// ---------- block reductions (256 threads) ----------
__device__ __forceinline__ float blk_sum256(float v, float* red) {
  int t = threadIdx.x;
  red[t] = v; __syncthreads();
  #pragma unroll
  for (int off = 128; off > 0; off >>= 1) {
    if (t < off) red[t] += red[t + off];
    __syncthreads();
  }
  float r = red[0]; __syncthreads();
  return r;
}

// ---------- staging helpers: 8 contiguous elements -> bf16 LDS ----------
__device__ __forceinline__ void stage8(const ushort* __restrict__ src, ushort* dst) {
  *(uint4*)dst = *(const uint4*)src;
}
__device__ __forceinline__ void stage8(const float* __restrict__ src, ushort* dst) {
  float4 a = ((const float4*)src)[0];
  float4 b = ((const float4*)src)[1];
  ushort4 o0, o1;
  o0.x = f2b(a.x); o0.y = f2b(a.y); o0.z = f2b(a.z); o0.w = f2b(a.w);
  o1.x = f2b(b.x); o1.y = f2b(b.y); o1.z = f2b(b.z); o1.w = f2b(b.w);
  *(ushort4*)dst = o0;
  *(ushort4*)(dst + 4) = o1;
}

// ---------- bf16 MFMA GEMM: C[M,N] = act(A[M,K] @ B^T + bias) ----------
template<typename CT, typename AT, typename WT, bool VSPLIT, bool GATS>
__global__ __launch_bounds__(256) void mfma_gemm(
    const AT* __restrict__ A, int lda,
    const WT* __restrict__ Bw, int ldb,
    const float* __restrict__ bias,
    CT* __restrict__ C, int ldc, int K, int relu,
    ushort* __restrict__ VT,
    const float* __restrict__ asrcW, const float* __restrict__ adstW,
    float* __restrict__ ASRC, float* __restrict__ ADST)
{
  __shared__ ushort As[64][40];
  __shared__ ushort Bs[128][40];
  int tid = threadIdx.x;
  int lane = tid & 63, wave = tid >> 6;
  int wm = wave >> 1, wn = wave & 1;
  int quad = lane >> 4, l16 = lane & 15;
  long mBase = blockIdx.y * 64, nBase = blockIdx.x * 128;

  f32x4 zero4 = {0.f, 0.f, 0.f, 0.f};
  f32x4 acc[2][4];
  #pragma unroll
  for (int i = 0; i < 2; i++)
    #pragma unroll
    for (int j = 0; j < 4; j++) acc[i][j] = zero4;

  for (int k0 = 0; k0 < K; k0 += 32) {
    {
      int r = tid >> 2, sg = (tid & 3) * 8;
      stage8(A + (mBase + r) * lda + k0 + sg, &As[r][sg]);
    }
    #pragma unroll
    for (int p = 0; p < 2; p++) {
      int idx = p * 256 + tid;
      int r = idx >> 2, sg = (idx & 3) * 8;
      stage8(Bw + (nBase + r) * ldb + k0 + sg, &Bs[r][sg]);
    }
    __syncthreads();
    bf16x8 af[2], bfr[4];
    #pragma unroll
    for (int i = 0; i < 2; i++)
      af[i] = *(const bf16x8*)&As[wm * 32 + i * 16 + l16][quad * 8];
    #pragma unroll
    for (int j = 0; j < 4; j++)
      bfr[j] = *(const bf16x8*)&Bs[wn * 64 + j * 16 + l16][quad * 8];
    #pragma unroll
    for (int i = 0; i < 2; i++)
      #pragma unroll
      for (int j = 0; j < 4; j++)
        acc[i][j] = __builtin_amdgcn_mfma_f32_16x16x32_bf16(af[i], bfr[j], acc[i][j], 0, 0, 0);
    __syncthreads();
  }
  #pragma unroll
  for (int i = 0; i < 2; i++) {
    #pragma unroll
    for (int j = 0; j < 4; j++) {
      long col = nBase + wn * 64 + j * 16 + l16;
      float bv = bias ? bias[col] : 0.f;
      long row0 = mBase + wm * 32 + i * 16 + quad * 4;
      if (VSPLIT && col >= 512) {
        int cm = (int)col - 512, hh = cm >> 7, cc = cm & 127;
        long bidx = row0 >> 10, n0 = row0 & 1023;
        ushort4 o;
        o.x = f2b(acc[i][j][0] + bv);
        o.y = f2b(acc[i][j][1] + bv);
        o.z = f2b(acc[i][j][2] + bv);
        o.w = f2b(acc[i][j][3] + bv);
        *(ushort4*)&VT[(((bidx * 2 + hh) * 128 + cc) << 10) + n0] = o;
      } else {
        #pragma unroll
        for (int r = 0; r < 4; r++) {
          float v = acc[i][j][r] + bv;
          if (relu) v = fmaxf(v, 0.f);
          if constexpr (sizeof(CT) == 2) C[(row0 + r) * ldc + col] = f2b(v);
          else                           C[(row0 + r) * ldc + col] = v;
        }
      }
    }
  }
  if constexpr (GATS) {
    __shared__ float RS[64][2], RD[64][2];
    float ps[2][4], pd[2][4];
    #pragma unroll
    for (int i = 0; i < 2; i++)
      #pragma unroll
      for (int r = 0; r < 4; r++) { ps[i][r] = 0.f; pd[i][r] = 0.f; }
    #pragma unroll
    for (int j = 0; j < 4; j++) {
      long col = nBase + wn * 64 + j * 16 + l16;
      float ws = asrcW[col], wd = adstW[col];
      #pragma unroll
      for (int i = 0; i < 2; i++)
        #pragma unroll
        for (int r = 0; r < 4; r++) {
          ps[i][r] += acc[i][j][r] * ws;
          pd[i][r] += acc[i][j][r] * wd;
        }
    }
    #pragma unroll
    for (int off = 1; off < 16; off <<= 1)
      #pragma unroll
      for (int i = 0; i < 2; i++)
        #pragma unroll
        for (int r = 0; r < 4; r++) {
          ps[i][r] += __shfl_xor(ps[i][r], off);
          pd[i][r] += __shfl_xor(pd[i][r], off);
        }
    if (l16 == 0) {
      #pragma unroll
      for (int i = 0; i < 2; i++)
        #pragma unroll
        for (int r = 0; r < 4; r++) {
          int row = wm * 32 + i * 16 + quad * 4 + r;
          RS[row][wn] = ps[i][r];
          RD[row][wn] = pd[i][r];
        }
    }
    __syncthreads();
    if (tid < 64) {
      long gr = mBase + tid;
      ASRC[gr * 2 + blockIdx.x] = RS[tid][0] + RS[tid][1];
      ADST[gr * 2 + blockIdx.x] = RD[tid][0] + RD[tid][1];
    }
  }
}

template<typename CT, typename AT, typename WT>
static void mgemm(hipStream_t st, const AT* A, int lda, const WT* B, int ldb,
                  const float* bias, CT* C, int ldc, int M, int N, int K, int relu) {
  dim3 grid(N / 128, M / 64);
  mfma_gemm<CT, AT, WT, false, false><<<grid, 256, 0, st>>>(
      A, lda, B, ldb, bias, C, ldc, K, relu, nullptr, nullptr, nullptr, nullptr, nullptr);
}
template<typename AT, typename WT>
static void mgemm_vt(hipStream_t st, const AT* A, int lda, const WT* B, int ldb,
                     const float* bias, ushort* C, int ldc, int M, int N, int K, ushort* VT) {
  dim3 grid(N / 128, M / 64);
  mfma_gemm<ushort, AT, WT, true, false><<<grid, 256, 0, st>>>(
      A, lda, B, ldb, bias, C, ldc, K, 0, VT, nullptr, nullptr, nullptr, nullptr);
}
template<typename AT, typename WT>
static void mgemm_gat(hipStream_t st, const AT* A, int lda, const WT* B, int ldb,
                      float* C, int ldc, int M, int N, int K,
                      const float* asrcW, const float* adstW, float* AS, float* AD) {
  dim3 grid(N / 128, M / 64);
  mfma_gemm<float, AT, WT, false, true><<<grid, 256, 0, st>>>(
      A, lda, B, ldb, nullptr, C, ldc, K, 0, nullptr, asrcW, adstW, AS, AD);
}

// ---------- fused pos-embed MLP (MFMA, weights LDS-resident) ----------
__global__ __launch_bounds__(256) void pos_mlp(
    const float* __restrict__ cellp, const float* __restrict__ tab,
    const float* __restrict__ W1, const float* __restrict__ b1,
    const float* __restrict__ W2, const float* __restrict__ b2,
    float* __restrict__ X, ushort* __restrict__ Xb)
{
  __shared__ ushort Es[64][136];
  __shared__ ushort Bs[128][136];
  __shared__ ushort H1s[64][136];
  int tid = threadIdx.x;
  int lane = tid & 63, wave = tid >> 6;
  int wm = wave >> 1, wn = wave & 1;
  int quad = lane >> 4, l16 = lane & 15;
  int r0 = blockIdx.x * 64, c = blockIdx.y;

  #pragma unroll
  for (int p = 0; p < 4; p++) {
    int idx = p * 256 + tid;
    int r = idx >> 4, c8 = (idx & 15) * 8;
    float pos = cellp[(r0 + r) * 2 + c];
    pos = fminf(fmaxf(pos, 0.f), 1000.f);
    int pi = (int)pos;
    stage8(tab + ((long)(c * 1001 + pi)) * 128 + c8, &Es[r][c8]);
  }
  #pragma unroll
  for (int p = 0; p < 8; p++) {
    int idx = p * 256 + tid;
    int r = idx >> 4, c8 = (idx & 15) * 8;
    stage8(W1 + ((long)(c * 128 + r)) * 128 + c8, &Bs[r][c8]);
  }
  __syncthreads();

  f32x4 zero4 = {0.f, 0.f, 0.f, 0.f};
  f32x4 acc[2][4];
  #pragma unroll
  for (int i = 0; i < 2; i++)
    #pragma unroll
    for (int j = 0; j < 4; j++) acc[i][j] = zero4;
  #pragma unroll
  for (int ks = 0; ks < 4; ks++) {
    bf16x8 af[2], bfr[4];
    #pragma unroll
    for (int i = 0; i < 2; i++)
      af[i] = *(const bf16x8*)&Es[wm * 32 + i * 16 + l16][ks * 32 + quad * 8];
    #pragma unroll
    for (int j = 0; j < 4; j++)
      bfr[j] = *(const bf16x8*)&Bs[wn * 64 + j * 16 + l16][ks * 32 + quad * 8];
    #pragma unroll
    for (int i = 0; i < 2; i++)
      #pragma unroll
      for (int j = 0; j < 4; j++)
        acc[i][j] = __builtin_amdgcn_mfma_f32_16x16x32_bf16(af[i], bfr[j], acc[i][j], 0, 0, 0);
  }
  #pragma unroll
  for (int i = 0; i < 2; i++)
    #pragma unroll
    for (int j = 0; j < 4; j++) {
      int col = wn * 64 + j * 16 + l16;
      float bv = b1[c * 128 + col];
      #pragma unroll
      for (int r = 0; r < 4; r++) {
        int row = wm * 32 + i * 16 + quad * 4 + r;
        H1s[row][col] = f2b(fmaxf(acc[i][j][r] + bv, 0.f));
      }
    }
  __syncthreads();
  #pragma unroll
  for (int p = 0; p < 8; p++) {
    int idx = p * 256 + tid;
    int r = idx >> 4, c8 = (idx & 15) * 8;
    stage8(W2 + ((long)(c * 128 + r)) * 128 + c8, &Bs[r][c8]);
  }
  __syncthreads();
  #pragma unroll
  for (int i = 0; i < 2; i++)
    #pragma unroll
    for (int j = 0; j < 4; j++) acc[i][j] = zero4;
  #pragma unroll
  for (int ks = 0; ks < 4; ks++) {
    bf16x8 af[2], bfr[4];
    #pragma unroll
    for (int i = 0; i < 2; i++)
      af[i] = *(const bf16x8*)&H1s[wm * 32 + i * 16 + l16][ks * 32 + quad * 8];
    #pragma unroll
    for (int j = 0; j < 4; j++)
      bfr[j] = *(const bf16x8*)&Bs[wn * 64 + j * 16 + l16][ks * 32 + quad * 8];
    #pragma unroll
    for (int i = 0; i < 2; i++)
      #pragma unroll
      for (int j = 0; j < 4; j++)
        acc[i][j] = __builtin_amdgcn_mfma_f32_16x16x32_bf16(af[i], bfr[j], acc[i][j], 0, 0, 0);
  }
  #pragma unroll
  for (int i = 0; i < 2; i++)
    #pragma unroll
    for (int j = 0; j < 4; j++) {
      int col = wn * 64 + j * 16 + l16;
      float bv = b2[c * 128 + col];
      #pragma unroll
      for (int r = 0; r < 4; r++) {
        long row = r0 + wm * 32 + i * 16 + quad * 4 + r;
        long idx = row * 256 + c * 128 + col;
        float v = X[idx] + (acc[i][j][r] + bv);
        X[idx] = v;
        Xb[idx] = f2b(v);
      }
    }
}

// ---------- split-K skinny GEMM (M rows <= 16) ----------
template<int M_>
__global__ __launch_bounds__(256) void skinny_gemm(
    const float* __restrict__ A, int lda,
    const float* __restrict__ W, int K,
    float* __restrict__ P, int N, int slice)
{
  __shared__ float Asl[M_ * 192];
  __shared__ float Pr[4][M_][64];
  int tid = threadIdx.x;
  int ks = blockIdx.y;
  int kbeg = ks * slice;
  int kend = min(K, kbeg + slice);
  int sl = kend - kbeg;
  for (int idx = tid; idx < M_ * sl; idx += 256) {
    int m = idx / sl, k = idx - m * sl;
    Asl[m * sl + k] = A[(long)m * lda + kbeg + k];
  }
  __syncthreads();
  int n = blockIdx.x * 64 + (tid & 63);
  int sub = tid >> 6;
  int sl4 = (sl + 3) >> 2;
  int k0 = kbeg + sub * sl4;
  int k1 = min(kend, k0 + sl4);
  float acc[M_];
  #pragma unroll
  for (int m = 0; m < M_; m++) acc[m] = 0.f;
  if (n < N) {
    const float* wr = W + (long)n * K;
    for (int k = k0; k < k1; k++) {
      float w = wr[k];
      int kl = k - kbeg;
      #pragma unroll
      for (int m = 0; m < M_; m++) acc[m] += w * Asl[m * sl + kl];
    }
  }
  #pragma unroll
  for (int m = 0; m < M_; m++) Pr[sub][m][tid & 63] = acc[m];
  __syncthreads();
  if (sub == 0 && n < N) {
    #pragma unroll
    for (int m = 0; m < M_; m++) {
      float s = Pr[0][m][tid] + Pr[1][m][tid] + Pr[2][m][tid] + Pr[3][m][tid];
      P[((long)(ks * M_ + m)) * N + n] = s;
    }
  }
}

__global__ __launch_bounds__(256) void skinny_epi(
    const float* __restrict__ P, const float* __restrict__ bias,
    float* __restrict__ out, int M, int N, int KS, int relu)
{
  int idx = blockIdx.x * 256 + threadIdx.x;
  if (idx >= M * N) return;
  int m = idx / N, n = idx - m * N;
  float s = bias[n];
  for (int ks = 0; ks < KS; ks++) s += P[((long)(ks * M + m)) * N + n];
  if (relu) s = fmaxf(s, 0.f);
  out[(long)m * N + n] = s;
}

template<int M_>
static void sgemm(hipStream_t st, const float* A, int lda, const float* W, int K,
                  const float* bias, float* out, float* P, int N, int KS, int relu) {
  int slice = (K + KS - 1) / KS;
  dim3 grid((N + 63) / 64, KS);
  skinny_gemm<M_><<<grid, 256, 0, st>>>(A, lda, W, K, P, N, slice);
  skinny_epi<<<(M_ * N + 255) / 256, 256, 0, st>>>(P, bias, out, M_, N, KS, relu);
}

// ---------- bag stats: pn = (cellposes - mean) / (std + 1e-8) ----------
__global__ __launch_bounds__(256) void bag_stats(const float* __restrict__ cp, float* __restrict__ PN) {
  int b = blockIdx.x, tid = threadIdx.x;
  __shared__ float red[256];
  for (int c = 0; c < 2; c++) {
    float s = 0.f;
    for (int n = tid; n < 1024; n += 256) s += cp[((b << 10) + n) * 2 + c];
    float mean = blk_sum256(s, red) * (1.f / 1024.f);
    s = 0.f;
    for (int n = tid; n < 1024; n += 256) { float d = cp[((b << 10) + n) * 2 + c] - mean; s += d * d; }
    float var = blk_sum256(s, red) * (1.f / 1024.f);
    float inv = 1.f / (sqrtf(var) + 1e-8f);
    for (int n = tid; n < 1024; n += 256)
      PN[((b << 10) + n) * 2 + c] = (cp[((b << 10) + n) * 2 + c] - mean) * inv;
  }
}

// ---------- kNN: wave-cooperative iterative argmin (8x u64 shfl-min) ----------
__global__ __launch_bounds__(256) void knn_sel(const float* __restrict__ PN,
                                               int* __restrict__ NBR) {
  int blk = blockIdx.x;               // 512 blocks
  int b = blk >> 7, grp = blk & 127;  // 8 targets per block
  int tid = threadIdx.x;
  int wave = tid >> 6, lane = tid & 63;
  __shared__ float px[1024], py[1024];
  for (int i = tid; i < 1024; i += 256) {
    px[i] = PN[((b << 10) + i) * 2 + 0];
    py[i] = PN[((b << 10) + i) * 2 + 1];
  }
  __syncthreads();
  #pragma unroll
  for (int sub = 0; sub < 2; sub++) {
    int t = grp * 8 + wave * 2 + sub;
    float tx = px[t], ty = py[t];
    float dloc[16];
    #pragma unroll
    for (int k = 0; k < 16; k++) {
      int s = lane + (k << 6);
      float dx = __fadd_rn(px[s], -tx), dy = __fadd_rn(py[s], -ty);
      float d2 = __fadd_rn(__fadd_rn(__fmul_rn(dx, dx), __fmul_rn(dy, dy)), 1e-12f);
      dloc[k] = sqrtf(d2);
    }
    int res[8];
    #pragma unroll
    for (int it = 0; it < 8; it++) {
      float bd = dloc[0]; int bk = 0;
      #pragma unroll
      for (int k = 1; k < 16; k++)
        if (dloc[k] < bd) { bd = dloc[k]; bk = k; }
      unsigned long long key =
          (((unsigned long long)__float_as_uint(bd)) << 32) | (unsigned)(lane + (bk << 6));
      #pragma unroll
      for (int off = 1; off < 64; off <<= 1) {
        unsigned long long o = __shfl_xor(key, off);
        if (o < key) key = o;
      }
      int widx = (int)(key & 0xffffffffu);
      res[it] = widx;
      if ((widx & 63) == lane) dloc[widx >> 6] = 3.4e38f;
    }
    if (lane < 8) NBR[((long)((b << 10) + t)) * 8 + lane] = res[lane];
  }
}

// ---------- GAT aggregate + residual + LN ----------
__global__ __launch_bounds__(256) void gat_aggr_ln(
    const float* __restrict__ Hh, const float* __restrict__ ASRC, const float* __restrict__ ADST,
    const int* __restrict__ NBR, const float* __restrict__ gbias,
    const float* __restrict__ lng, const float* __restrict__ lnb,
    float* __restrict__ X, ushort* __restrict__ Xb)
{
  int row = blockIdx.x, tid = threadIdx.x;
  int b = row >> 10;
  __shared__ int nb[8];
  __shared__ float w[2][8];
  __shared__ float red[256];
  if (tid < 8) {
    int v = NBR[(long)row * 8 + tid];
    nb[tid] = min(max(v, 0), 1023);
  }
  __syncthreads();
  if (tid < 16) {
    int i = tid & 7, h = tid >> 3;
    float e = ADST[row * 2 + h] + ASRC[((b << 10) + nb[i]) * 2 + h];
    w[h][i] = (e >= 0.f) ? e : 0.2f * e;
  }
  __syncthreads();
  if (tid < 2) {
    float m = -3.4e38f;
    for (int i = 0; i < 8; i++) m = fmaxf(m, w[tid][i]);
    float s = 0.f;
    for (int i = 0; i < 8; i++) { float e = expf(w[tid][i] - m); w[tid][i] = e; s += e; }
    float inv = 1.f / s;
    for (int i = 0; i < 8; i++) w[tid][i] *= inv;
  }
  __syncthreads();
  int h = tid >> 7, c = tid & 127;
  float acc = 0.f;
  #pragma unroll
  for (int i = 0; i < 8; i++)
    acc += w[h][i] * Hh[((long)((b << 10) + nb[i])) * 256 + h * 128 + c];
  float v = acc + gbias[tid] + X[(long)row * 256 + tid];
  float mean = blk_sum256(v, red) * (1.f / 256.f);
  float dv = v - mean;
  float var = blk_sum256(dv * dv, red) * (1.f / 256.f);
  float o = dv * rsqrtf(var + 1e-5f) * lng[tid] + lnb[tid];
  X[(long)row * 256 + tid] = o;
  Xb[(long)row * 256 + tid] = f2b(o);
}

// ---------- residual + LayerNorm, D=256, one wave per row ----------
__global__ __launch_bounds__(256) void add_ln4(const float* __restrict__ res,
    const float* __restrict__ Yv, const float* __restrict__ g, const float* __restrict__ b,
    float* __restrict__ out, ushort* __restrict__ outb)
{
  int wave = threadIdx.x >> 6, lane = threadIdx.x & 63;
  long row = blockIdx.x * 4 + wave;
  const float* yr = Yv + row * 256;
  const float* rr = res ? res + row * 256 : nullptr;
  float v[4];
  float s = 0.f;
  #pragma unroll
  for (int i = 0; i < 4; i++) {
    int d = lane + i * 64;
    float x = yr[d];
    if (rr) x += rr[d];
    v[i] = x; s += x;
  }
  #pragma unroll
  for (int off = 32; off > 0; off >>= 1) s += __shfl_xor(s, off);
  float mean = s * (1.f / 256.f);
  float vs = 0.f;
  #pragma unroll
  for (int i = 0; i < 4; i++) { float dv = v[i] - mean; vs += dv * dv; }
  #pragma unroll
  for (int off = 32; off > 0; off >>= 1) vs += __shfl_xor(vs, off);
  float rstd = rsqrtf(vs * (1.f / 256.f) + 1e-5f);
  #pragma unroll
  for (int i = 0; i < 4; i++) {
    int d = lane + i * 64;
    float o = (v[i] - mean) * rstd * g[d] + b[d];
    out[row * 256 + d] = o;
    if (outb) outb[row * 256 + d] = f2b(o);
  }
}

// ---------- LayerNorm (D=1024, head rows) ----------
__global__ __launch_bounds__(256) void add_ln_big(const float* __restrict__ Yv,
    const float* __restrict__ g, const float* __restrict__ b,
    float* __restrict__ out)
{
  int row = blockIdx.x, tid = threadIdx.x;
  __shared__ float red[256];
  float vals[4];
  float s = 0.f;
  #pragma unroll
  for (int i = 0; i < 4; i++) {
    int d = tid + (i << 8);
    float v = Yv[(long)row * 1024 + d];
    vals[i] = v; s += v;
  }
  float mean = blk_sum256(s, red) * (1.f / 1024.f);
  s = 0.f;
  #pragma unroll
  for (int i = 0; i < 4; i++) { float dv = vals[i] - mean; s += dv * dv; }
  float var = blk_sum256(s, red) * (1.f / 1024.f);
  float rstd = rsqrtf(var + 1e-5f);
  #pragma unroll
  for (int i = 0; i < 4; i++) {
    int d = tid + (i << 8);
    out[(long)row * 1024 + d] = (vals[i] - mean) * rstd * g[d] + b[d];
  }
}

// ---------- split-K MFMA flash attention: partials over half the keys ----------
// 256 blocks = (qt*2+half)*8 + bh (blk%8 == bh -> XCD swizzle preserved).
// Inner loop identical to the proven R15 structure. Writes partial m,l (fp32)
// and O-accumulator (bf16) for the merge kernel.
__global__ __launch_bounds__(256) void flash_part(const ushort* __restrict__ QKV,
                                                  const ushort* __restrict__ VT,
                                                  ushort* __restrict__ OP,
                                                  float* __restrict__ Mp,
                                                  float* __restrict__ Lp)
{
  const float scale = 0.08838834764831845f;
  int blk = blockIdx.x;
  int bh = blk & 7, rest = blk >> 3;
  int half = rest & 1, qt = rest >> 1;
  int b = bh >> 1, h = bh & 1;
  const ushort* qkg = QKV + (long)b * 1024 * 768 + h * 128;
  const ushort* vtg = VT + ((long)bh << 17);

  __shared__ ushort Qs[64][136];
  __shared__ ushort Ks[64][136];
  __shared__ ushort Vt[128][72];
  __shared__ ushort Ps[4][16][72];

  int tid = threadIdx.x;
  int wave = tid >> 6, lane = tid & 63;
  int quad = lane >> 4, l16 = lane & 15;

  #pragma unroll
  for (int p = 0; p < 4; p++) {
    int idx = p * 256 + tid;
    int r = idx >> 4, c8 = (idx & 15) * 8;
    *(uint4*)&Qs[r][c8] = *(const uint4*)(qkg + (long)(qt * 64 + r) * 768 + c8);
  }
  __syncthreads();
  bf16x8 af[4];
  #pragma unroll
  for (int ks = 0; ks < 4; ks++)
    af[ks] = *(const bf16x8*)&Qs[wave * 16 + l16][ks * 32 + quad * 8];

  f32x4 Oacc[8];
  f32x4 zero4 = {0.f, 0.f, 0.f, 0.f};
  #pragma unroll
  for (int j = 0; j < 8; j++) Oacc[j] = zero4;
  float mr[4], lr[4];
  #pragma unroll
  for (int r = 0; r < 4; r++) { mr[r] = -3.4e38f; lr[r] = 0.f; }

  int kt0 = half * 8;
  for (int kt = kt0; kt < kt0 + 8; kt++) {
    __syncthreads();
    #pragma unroll
    for (int p = 0; p < 4; p++) {
      int idx = p * 256 + tid;
      int r = idx >> 4, c8 = (idx & 15) * 8;
      *(uint4*)&Ks[r][c8] = *(const uint4*)(qkg + (long)(kt * 64 + r) * 768 + 256 + c8);
      int c = idx >> 3, k8 = (idx & 7) * 8;
      *(uint4*)&Vt[c][k8] = *(const uint4*)(vtg + ((long)c << 10) + kt * 64 + k8);
    }
    __syncthreads();
    f32x4 acc[4];
    #pragma unroll
    for (int j = 0; j < 4; j++) acc[j] = zero4;
    #pragma unroll
    for (int ks = 0; ks < 4; ks++) {
      #pragma unroll
      for (int j = 0; j < 4; j++) {
        bf16x8 kb = *(const bf16x8*)&Ks[j * 16 + l16][ks * 32 + quad * 8];
        acc[j] = __builtin_amdgcn_mfma_f32_16x16x32_bf16(af[ks], kb, acc[j], 0, 0, 0);
      }
    }
    float sv[4][4], tmax[4];
    #pragma unroll
    for (int r = 0; r < 4; r++) tmax[r] = -3.4e38f;
    #pragma unroll
    for (int j = 0; j < 4; j++)
      #pragma unroll
      for (int r = 0; r < 4; r++) {
        float x = acc[j][r] * scale;
        sv[j][r] = x;
        tmax[r] = fmaxf(tmax[r], x);
      }
    #pragma unroll
    for (int off = 1; off < 16; off <<= 1)
      #pragma unroll
      for (int r = 0; r < 4; r++) tmax[r] = fmaxf(tmax[r], __shfl_xor(tmax[r], off));
    float alpha[4], rsum[4];
    #pragma unroll
    for (int r = 0; r < 4; r++) {
      float mn = fmaxf(mr[r], tmax[r]);
      alpha[r] = expf(mr[r] - mn);
      mr[r] = mn;
      rsum[r] = 0.f;
    }
    #pragma unroll
    for (int j = 0; j < 4; j++)
      #pragma unroll
      for (int r = 0; r < 4; r++) {
        float p = expf(sv[j][r] - mr[r]);
        sv[j][r] = p;
        rsum[r] += p;
      }
    #pragma unroll
    for (int off = 1; off < 16; off <<= 1)
      #pragma unroll
      for (int r = 0; r < 4; r++) rsum[r] += __shfl_xor(rsum[r], off);
    #pragma unroll
    for (int r = 0; r < 4; r++) lr[r] = lr[r] * alpha[r] + rsum[r];
    #pragma unroll
    for (int j = 0; j < 4; j++)
      #pragma unroll
      for (int r = 0; r < 4; r++)
        Ps[wave][quad * 4 + r][j * 16 + l16] = f2b(sv[j][r]);
    #pragma unroll
    for (int jj = 0; jj < 8; jj++)
      #pragma unroll
      for (int r = 0; r < 4; r++) Oacc[jj][r] *= alpha[r];
    __syncthreads();
    #pragma unroll
    for (int s = 0; s < 2; s++) {
      bf16x8 pa = *(const bf16x8*)&Ps[wave][l16][s * 32 + quad * 8];
      #pragma unroll
      for (int jj = 0; jj < 8; jj++) {
        bf16x8 vb = *(const bf16x8*)&Vt[jj * 16 + l16][s * 32 + quad * 8];
        Oacc[jj] = __builtin_amdgcn_mfma_f32_16x16x32_bf16(pa, vb, Oacc[jj], 0, 0, 0);
      }
    }
  }
  // write partials: O (bf16, unnormalized), m, l per local row
  long pbase = (long)blk * 64;
  #pragma unroll
  for (int jj = 0; jj < 8; jj++) {
    int col = jj * 16 + l16;
    #pragma unroll
    for (int r = 0; r < 4; r++) {
      int lrow = wave * 16 + quad * 4 + r;
      OP[(pbase + lrow) * 128 + col] = f2b(Oacc[jj][r]);
    }
  }
  if (l16 == 0) {
    #pragma unroll
    for (int r = 0; r < 4; r++) {
      int lrow = wave * 16 + quad * 4 + r;
      Mp[pbase + lrow] = mr[r];
      Lp[pbase + lrow] = lr[r];
    }
  }
}

// merge two key-half partials -> final O (bf16)
__global__ __launch_bounds__(256) void flash_merge(const ushort* __restrict__ OP,
                                                   const float* __restrict__ Mp,
                                                   const float* __restrict__ Lp,
                                                   ushort* __restrict__ O)
{
  int blk = blockIdx.x;              // 128 = qt*8 + bh
  int bh = blk & 7, qt = blk >> 3;
  int b = bh >> 1, h = bh & 1;
  int p0 = (qt * 2 + 0) * 8 + bh;
  int p1 = (qt * 2 + 1) * 8 + bh;
  int tid = threadIdx.x;
  int r = tid >> 2, c0 = (tid & 3) * 32;
  float m0 = Mp[p0 * 64 + r], m1 = Mp[p1 * 64 + r];
  float l0 = Lp[p0 * 64 + r], l1 = Lp[p1 * 64 + r];
  float mm = fmaxf(m0, m1);
  float w0 = expf(m0 - mm), w1 = expf(m1 - mm);
  float inv = 1.f / (w0 * l0 + w1 * l1);
  const ushort* o0 = OP + ((long)(p0 * 64 + r)) * 128;
  const ushort* o1 = OP + ((long)(p1 * 64 + r)) * 128;
  ushort* od = O + ((long)(b * 1024 + qt * 64 + r)) * 256 + h * 128;
  #pragma unroll 8
  for (int c = c0; c < c0 + 32; c++) {
    float o = w0 * b2f(o0[c]) + w1 * b2f(o1[c]);
    od[c] = f2b(o * inv);
  }
}

// ---------- split-K pooling attention ----------
__global__ __launch_bounds__(128) void pool_split(
    const float* __restrict__ qe, const float* __restrict__ pinW, const float* __restrict__ pinB,
    const float* __restrict__ srand, const ushort* __restrict__ KV,
    float* __restrict__ PM, float* __restrict__ PL, float* __restrict__ PO)
{
  int cid = blockIdx.x;
  int id = blockIdx.y;
  int h = id & 1, nq = (id >> 1) & 3, b = id >> 3;
  int tid = threadIdx.x;
  __shared__ float qs[128];
  __shared__ float eg[128];
  __shared__ float red[128];
  {
    float a = pinB[h * 128 + tid];
    const float* wr = pinW + ((long)(h * 128 + tid)) * 256;
    const float* qr = qe + nq * 256;
    for (int i = 0; i < 256; i++) a += qr[i] * wr[i];
    qs[tid] = a;
  }
  __syncthreads();
  const float scale = 0.08838834764831845f;
  int s = cid * 128 + tid;
  float d = 0.f;
  {
    const ushort* kr = KV + ((long)((b << 10) + s)) * 512 + h * 128;
    #pragma unroll
    for (int c8 = 0; c8 < 128; c8 += 8) {
      uint4 kv4 = *(const uint4*)(kr + c8);
      const ushort* kp = (const ushort*)&kv4;
      #pragma unroll
      for (int j = 0; j < 8; j++) d += qs[c8 + j] * b2f(kp[j]);
    }
  }
  float lg = d * scale + ((srand[nq * 1024 + s] < 0.3f) ? 0.f : -1e9f);
  red[tid] = lg; __syncthreads();
  for (int off = 64; off > 0; off >>= 1) { if (tid < off) red[tid] = fmaxf(red[tid], red[tid + off]); __syncthreads(); }
  float m = red[0]; __syncthreads();
  float e = expf(lg - m);
  eg[tid] = e;
  red[tid] = e; __syncthreads();
  for (int off = 64; off > 0; off >>= 1) { if (tid < off) red[tid] += red[tid + off]; __syncthreads(); }
  float l = red[0];
  __syncthreads();
  float o = 0.f;
  const ushort* vbase = KV + ((long)((b << 10) + cid * 128)) * 512 + 256 + h * 128 + tid;
  for (int ss = 0; ss < 128; ss++)
    o += eg[ss] * b2f(vbase[(long)ss * 512]);
  int part = id * 8 + cid;
  PO[(long)part * 128 + tid] = o;
  if (tid == 0) { PM[part] = m; PL[part] = l; }
}

__global__ __launch_bounds__(128) void pool_merge(
    const float* __restrict__ PM, const float* __restrict__ PL, const float* __restrict__ PO,
    float* __restrict__ ATTP)
{
  int id = blockIdx.x;
  int h = id & 1, nq = (id >> 1) & 3, b = id >> 3;
  int tid = threadIdx.x;
  float m = -3.4e38f;
  #pragma unroll
  for (int c = 0; c < 8; c++) m = fmaxf(m, PM[id * 8 + c]);
  float l = 0.f, o = 0.f;
  #pragma unroll
  for (int c = 0; c < 8; c++) {
    float w = expf(PM[id * 8 + c] - m);
    l += PL[id * 8 + c] * w;
    o += PO[(long)(id * 8 + c) * 128 + tid] * w;
  }
  ATTP[(b * 4 + nq) * 256 + h * 128 + tid] = o / l;
}

// ---------- column-mean partials ----------
__global__ __launch_bounds__(256) void col_mean_part(const float* __restrict__ X,
                                                     float* __restrict__ PSUM)
{
  int blk = blockIdx.x;
  int b = blk >> 4, ch = blk & 15;
  int d = threadIdx.x;
  float s = 0.f;
  int n0 = ch * 64;
  const float* xr = X + ((long)((b << 10) + n0)) * 256 + d;
  #pragma unroll 4
  for (int n = 0; n < 64; n++) s += xr[(long)n * 256];
  PSUM[(long)blk * 256 + d] = s;
}

__global__ __launch_bounds__(256) void combined_merge(const float* __restrict__ PSUM,
    const float* __restrict__ ATTO, float* __restrict__ CMB)
{
  int b = blockIdx.x, d = threadIdx.x;
  float s = 0.f;
  #pragma unroll
  for (int ch = 0; ch < 16; ch++) s += PSUM[(long)(b * 16 + ch) * 256 + d];
  CMB[b * 1280 + d] = s * (1.f / 1024.f);
  #pragma unroll
  for (int q = 0; q < 4; q++)
    CMB[b * 1280 + 256 + q * 256 + d] = ATTO[(b * 4 + q) * 256 + d];
}

__global__ void store_out(const float* __restrict__ src, float* __restrict__ dst, int n) {
  int i = blockIdx.x * blockDim.x + threadIdx.x;
  if (i < n) dst[i] = src[i];
}
__global__ void fill_out_zero(float* __restrict__ dst, int n) {
  int i = blockIdx.x * blockDim.x + threadIdx.x;
  if (i < n) dst[i] = 0.f;
}

extern "C" void kernel_launch(void* const* d_in, const int* in_sizes, int n_in,
                              void* d_out, int out_size, void* d_ws, size_t ws_size,
                              hipStream_t stream)
{
  const float* inp      = (const float*)d_in[0];
  const float* cellp    = (const float*)d_in[1];
  const float* srand    = (const float*)d_in[2];
  const float* emb_W    = (const float*)d_in[3];
  const float* emb_b    = (const float*)d_in[4];
  const float* pe_tab   = (const float*)d_in[5];
  const float* pe_W1    = (const float*)d_in[6];
  const float* pe_b1    = (const float*)d_in[7];
  const float* pe_W2    = (const float*)d_in[8];
  const float* pe_b2    = (const float*)d_in[9];
  const float* gat_W    = (const float*)d_in[10];
  const float* gat_asrc = (const float*)d_in[11];
  const float* gat_adst = (const float*)d_in[12];
  const float* gat_b    = (const float*)d_in[13];
  const float* ln_g     = (const float*)d_in[14];
  const float* ln_b     = (const float*)d_in[15];
  const float* qkv_W    = (const float*)d_in[16];
  const float* qkv_b    = (const float*)d_in[17];
  const float* out_W    = (const float*)d_in[18];
  const float* out_b    = (const float*)d_in[19];
  const float* ff1_W    = (const float*)d_in[20];
  const float* ff1_b    = (const float*)d_in[21];
  const float* ff2_W    = (const float*)d_in[22];
  const float* ff2_b    = (const float*)d_in[23];
  const float* ln1_g    = (const float*)d_in[24];
  const float* ln1_b    = (const float*)d_in[25];
  const float* ln2_g    = (const float*)d_in[26];
  const float* ln2_b    = (const float*)d_in[27];
  const float* q_emb    = (const float*)d_in[28];
  const float* pin_W    = (const float*)d_in[29];
  const float* pin_b    = (const float*)d_in[30];
  const float* pout_W   = (const float*)d_in[31];
  const float* pout_b   = (const float*)d_in[32];
  const float* m1_W     = (const float*)d_in[33];
  const float* m1_b     = (const float*)d_in[34];
  const float* mln1_g   = (const float*)d_in[35];
  const float* mln1_b   = (const float*)d_in[36];
  const float* m2_W     = (const float*)d_in[37];
  const float* m2_b     = (const float*)d_in[38];
  const float* mln2_g   = (const float*)d_in[39];
  const float* mln2_b   = (const float*)d_in[40];
  const float* m3_W     = (const float*)d_in[41];
  const float* m3_b     = (const float*)d_in[42];
  const float* c1_W     = (const float*)d_in[43];
  const float* c1_b     = (const float*)d_in[44];
  const float* c2_W     = (const float*)d_in[45];
  const float* c2_b     = (const float*)d_in[46];
  const float* c3_W     = (const float*)d_in[47];
  const float* c3_b     = (const float*)d_in[48];
  const float* c4_W     = (const float*)d_in[49];
  const float* c4_b     = (const float*)d_in[50];
  (void)in_sizes; (void)n_in;

  // ---- workspace (bytes, 256-aligned; ~20.7 MB) ----
  char* base = (char*)d_ws;
  size_t off = 0;
  auto alloc = [&](size_t bytes) { void* p = base + off; off += (bytes + 255) & ~size_t(255); return p; };
  float* PN    = (float*)alloc(32768);
  float* AS    = (float*)alloc(32768);
  float* AD    = (float*)alloc(32768);
  float* ATTP  = (float*)alloc(16384);
  float* ATTO  = (float*)alloc(16384);
  float* CMB   = (float*)alloc(20480);
  float* Ha    = (float*)alloc(16384);
  float* Hb    = (float*)alloc(16384);
  float* Hc    = (float*)alloc(16640);
  float* Hd    = (float*)alloc(8192);
  float* He    = (float*)alloc(4096);
  float* Hf    = (float*)alloc(512);
  float* Pk    = (float*)alloc(262144);           // head split-K partials | flash m/l
  float* PPM   = (float*)alloc(1024);
  float* PPL   = (float*)alloc(1024);
  float* PPO   = (float*)alloc(131072);
  float* PSUM  = (float*)alloc(65536);
  int*   NBR   = (int*)alloc(131072);
  float* X     = (float*)alloc(4194304);
  ushort* Xb   = (ushort*)alloc(2097152);
  char*  Rq    = (char*)alloc(6291456);           // QKVb | F2 | KVb
  char*  Rf    = (char*)alloc(4194304);           // Ob | VT | FFBb(lo)
  float*  F1   = (float*)alloc(4194304);          // GAT h | flash O-partials | FFBb(hi)
  ushort* QKVb = (ushort*)Rq;
  float*  F2   = (float*)Rq;
  ushort* KVb  = (ushort*)Rq;
  ushort* Ob   = (ushort*)Rf;
  ushort* VT   = (ushort*)(Rf + 2097152);
  ushort* FFBb = (ushort*)Rf;                     // [4096,1024] bf16 spans Rf+F1
  ushort* OPrt = (ushort*)F1;                     // flash O-partials [256][64][128] bf16 = 4MB
  float*  Mprt = Pk;                              // [256*64] fp32 = 64KB
  float*  Lprt = Pk + 16384;                      // [256*64] fp32 = 64KB
  if (ws_size < off) { fill_out_zero<<<1, 128, 0, stream>>>((float*)d_out, out_size); return; }

  // ---- graph construction ----
  bag_stats<<<4, 256, 0, stream>>>(cellp, PN);
  knn_sel<<<512, 256, 0, stream>>>(PN, NBR);

  // ---- embedding + positional MLP (MFMA; emits X and Xb) ----
  mgemm<float>(stream, inp, 512, emb_W, 512, emb_b, X, 256, 4096, 256, 512, 0);
  pos_mlp<<<dim3(64, 2), 256, 0, stream>>>(cellp, pe_tab, pe_W1, pe_b1, pe_W2, pe_b2, X, Xb);

  // ---- 2x GAT (scores fused into GEMM epilogue) ----
  for (int l = 0; l < 2; l++) {
    mgemm_gat(stream, Xb, 256, gat_W + l * 65536, 256, F1, 256, 4096, 256, 256,
              gat_asrc + l * 256, gat_adst + l * 256, AS, AD);
    gat_aggr_ln<<<4096, 256, 0, stream>>>(F1, AS, AD, NBR, gat_b + l * 256, ln_g, ln_b, X, Xb);
  }

  // ---- 2x Transformer encoder layer (split-K flash, single-chunk FFN) ----
  for (int l = 0; l < 2; l++) {
    mgemm_vt(stream, Xb, 256, qkv_W + (long)l * 768 * 256, 256, qkv_b + l * 768,
             QKVb, 768, 4096, 768, 256, VT);
    flash_part<<<256, 256, 0, stream>>>(QKVb, VT, OPrt, Mprt, Lprt);
    flash_merge<<<128, 256, 0, stream>>>(OPrt, Mprt, Lprt, Ob);
    mgemm<float>(stream, Ob, 256, out_W + l * 65536, 256, out_b + l * 256, F2, 256,
                 4096, 256, 256, 0);
    add_ln4<<<1024, 256, 0, stream>>>(X, F2, ln1_g + l * 256, ln1_b + l * 256, X, Xb);
    mgemm<ushort>(stream, Xb, 256, ff1_W + l * 262144, 256, ff1_b + l * 1024,
                  FFBb, 1024, 4096, 1024, 256, 1);
    mgemm<float>(stream, FFBb, 1024, ff2_W + l * 262144, 1024, ff2_b + l * 256,
                 F2, 256, 4096, 256, 1024, 0);
    add_ln4<<<1024, 256, 0, stream>>>(X, F2, ln2_g + l * 256, ln2_b + l * 256, X, Xb);
  }

  // ---- final LN ----
  add_ln4<<<1024, 256, 0, stream>>>((const float*)nullptr, X, ln_g, ln_b, X, Xb);

  // ---- pooling (split-K flash-decode style) ----
  mgemm<ushort>(stream, Xb, 256, pin_W + 65536, 256, pin_b + 256, KVb, 512, 4096, 512, 256, 0);
  pool_split<<<dim3(8, 32), 128, 0, stream>>>(q_emb, pin_W, pin_b, srand, KVb, PPM, PPL, PPO);
  pool_merge<<<32, 128, 0, stream>>>(PPM, PPL, PPO, ATTP);
  sgemm<16>(stream, ATTP, 256, pout_W, 256, pout_b, ATTO, Pk, 256, 2, 0);
  col_mean_part<<<64, 256, 0, stream>>>(X, PSUM);
  combined_merge<<<4, 256, 0, stream>>>(PSUM, ATTO, CMB);

  // ---- MLP head (fp32, split-K skinny GEMMs) ----
  sgemm<4>(stream, CMB, 1280, m1_W, 1280, m1_b, Ha, Pk, 1024, 8, 1);
  add_ln_big<<<4, 256, 0, stream>>>(Ha, mln1_g, mln1_b, Ha);
  sgemm<4>(stream, Ha, 1024, m2_W, 1024, m2_b, Hb, Pk, 1024, 8, 1);
  add_ln_big<<<4, 256, 0, stream>>>(Hb, mln2_g, mln2_b, Hb);
  sgemm<4>(stream, Hb, 1024, m3_W, 1024, m3_b, Ha, Pk, 1024, 8, 0);
  sgemm<4>(stream, Ha, 1024, c1_W, 1024, c1_b, Hc, Pk, 1032, 8, 1);
  sgemm<4>(stream, Hc, 1032, c2_W, 1032, c2_b, Hd, Pk, 512, 8, 1);
  sgemm<4>(stream, Hd, 512, c3_W, 512, c3_b, He, Pk, 256, 4, 1);
  sgemm<4>(stream, He, 256, c4_W, 256, c4_b, Hf, Pk, 24, 2, 0);
  store_out<<<1, 128, 0, stream>>>(Hf, (float*)d_out, out_size);
}